// Round 2
// baseline (695.713 us; speedup 1.0000x reference)
//
#include <hip/hip_runtime.h>

// B=2, L=128, E=1024, H=16, G=8, D=64, R=2, BL=256 rows total.
// All inputs/outputs are float32 (per reference dtypes).

// ---------------------------------------------------------------------------
// K1: q = Q@Wq+bq [256,1024], k = K@Wk+bk [256,512], v = V@Wv+bv [256,512]
// grid (16 col-tiles, 16 row-tiles), 256 threads.
// col tiles 0..7 -> q, 8..11 -> k, 12..15 -> v
__global__ __launch_bounds__(256) void k_qkv(
    const float* __restrict__ Q, const float* __restrict__ K, const float* __restrict__ V,
    const float* __restrict__ Wq, const float* __restrict__ bq,
    const float* __restrict__ Wk, const float* __restrict__ bk,
    const float* __restrict__ Wv, const float* __restrict__ bv,
    float* __restrict__ q_ws, float* __restrict__ k_ws, float* __restrict__ v_ws)
{
  __shared__ float xs[16][1024];   // 64 KB
  int ct = blockIdx.x, rt = blockIdx.y, tid = threadIdx.x;
  const float* X; const float* W; const float* bias; int ldW, c0w; float* out; int ldO;
  if (ct < 8)       { X = Q; W = Wq; bias = bq; ldW = 1024; c0w = ct * 128;        out = q_ws; ldO = 1024; }
  else if (ct < 12) { X = K; W = Wk; bias = bk; ldW = 512;  c0w = (ct - 8) * 128;  out = k_ws; ldO = 512; }
  else              { X = V; W = Wv; bias = bv; ldW = 512;  c0w = (ct - 12) * 128; out = v_ws; ldO = 512; }
  int row0 = rt * 16;
  for (int f = tid; f < 16 * 256; f += 256) {
    int rr = f >> 8, c4 = f & 255;
    *(float4*)&xs[rr][c4 * 4] = *(const float4*)(X + (row0 + rr) * 1024 + c4 * 4);
  }
  __syncthreads();
  int cl = tid & 127, rs = tid >> 7;
  int col = c0w + cl;
  float acc[8] = {0, 0, 0, 0, 0, 0, 0, 0};
  for (int e = 0; e < 1024; e += 2) {
    float w0 = W[e * ldW + col];
    float w1 = W[(e + 1) * ldW + col];
#pragma unroll
    for (int r = 0; r < 8; r++) {
      float2 x2 = *(const float2*)&xs[rs * 8 + r][e];
      acc[r] += x2.x * w0 + x2.y * w1;
    }
  }
  float bb = bias[col];
#pragma unroll
  for (int r = 0; r < 8; r++) out[(row0 + rs * 8 + r) * ldO + col] = acc[r] + bb;
}

// ---------------------------------------------------------------------------
// K1b: A[r,h] = (q[r,h,:]·k[r,g,:] + q[r,h,:]·brk[g,:]) / 8
__global__ __launch_bounds__(256) void k_base(
    const float* __restrict__ q_ws, const float* __restrict__ k_ws,
    const float* __restrict__ brk, float* __restrict__ A_ws)
{
  int t = blockIdx.x * 256 + threadIdx.x;  // 4096
  int r = t >> 4, h = t & 15, g = h >> 1;
  const float* qp = q_ws + r * 1024 + h * 64;
  const float* kp = k_ws + r * 512 + g * 64;
  const float* bp = brk + g * 64;
  float s = 0.f;
  for (int d = 0; d < 64; d++) s += qp[d] * (kp[d] + bp[d]);
  A_ws[t] = s * 0.125f;
}

// ---------------------------------------------------------------------------
// K1c: u'[r,h,e] = (1/8) * sum_d q[r,h,d] * Wrk[e, g*64+d]
// grid (8 e-tiles of 128, 32 row-tiles of 8), 256 threads. LDS = 32+32 = 64 KB.
__global__ __launch_bounds__(256) void k_uproj(
    const float* __restrict__ q_ws, const float* __restrict__ Wrk, float* __restrict__ u_ws)
{
  __shared__ float qs[8][1024];    // 32 KB
  __shared__ float wt[64][128];    // 32 KB  [d][e_local]
  int et = blockIdx.x, rt = blockIdx.y, tid = threadIdx.x;
  int row0 = rt * 8, e0 = et * 128;
  for (int f = tid; f < 8 * 256; f += 256) {
    int rr = f >> 8, c4 = f & 255;
    *(float4*)&qs[rr][c4 * 4] = *(const float4*)(q_ws + (row0 + rr) * 1024 + c4 * 4);
  }
  int el = tid & 127, rs = tid >> 7;
  for (int g = 0; g < 8; g++) {
    __syncthreads();
    for (int f = tid; f < 128 * 16; f += 256) {
      int er = f >> 4, dg = f & 15;
      float4 p = *(const float4*)(Wrk + (e0 + er) * 512 + g * 64 + dg * 4);
      wt[dg * 4 + 0][er] = p.x; wt[dg * 4 + 1][er] = p.y;
      wt[dg * 4 + 2][er] = p.z; wt[dg * 4 + 3][er] = p.w;
    }
    __syncthreads();
    float acc[8];
#pragma unroll
    for (int i = 0; i < 8; i++) acc[i] = 0.f;
    for (int d = 0; d < 64; d += 2) {
      float w0 = wt[d][el], w1 = wt[d + 1][el];
#pragma unroll
      for (int rowi = 0; rowi < 4; rowi++) {
        float2 q0 = *(const float2*)&qs[rs * 4 + rowi][g * 128 + d];
        float2 q1 = *(const float2*)&qs[rs * 4 + rowi][g * 128 + 64 + d];
        acc[rowi * 2 + 0] += q0.x * w0 + q0.y * w1;
        acc[rowi * 2 + 1] += q1.x * w0 + q1.y * w1;
      }
    }
#pragma unroll
    for (int rowi = 0; rowi < 4; rowi++)
#pragma unroll
      for (int rq = 0; rq < 2; rq++)
        u_ws[((row0 + rs * 4 + rowi) * 16 + (g * 2 + rq)) * 1024 + e0 + el] = acc[rowi * 2 + rq] * 0.125f;
  }
}

// ---------------------------------------------------------------------------
// K2: per (b,i): LN-folded scores, local softmax stats, unnormalized weighted sum
// score[h,j] = A[h] + rstd_j*(x_j·(g∘u_h) - mu_j*Gu_h) + Bu_h
// w_un[h,e] = g_e*(sum_j p2_j x_je - C1_h) + b_e*Z_h,  p2_j = exp(s-M)*rstd_j
__global__ __launch_bounds__(256) void k_attn(
    const float* __restrict__ rpe, const float* __restrict__ lng, const float* __restrict__ lnb,
    const float* __restrict__ u_ws, const float* __restrict__ A_ws,
    float* __restrict__ M_ws, float* __restrict__ Z_ws, float* __restrict__ w_ws)
{
  __shared__ float sbuf[16][128];
  __shared__ float muS[128], rsS[128];
  __shared__ float ZhS[16], C1S[16];
  int rr = blockIdx.x, tid = threadIdx.x;
  int w = tid >> 6, lane = tid & 63;
  int e0 = lane * 16;

  float gv[16], bvv[16];
#pragma unroll
  for (int s = 0; s < 16; s += 4) {
    float4 g4 = *(const float4*)(lng + e0 + s);
    gv[s] = g4.x; gv[s + 1] = g4.y; gv[s + 2] = g4.z; gv[s + 3] = g4.w;
    float4 b4 = *(const float4*)(lnb + e0 + s);
    bvv[s] = b4.x; bvv[s + 1] = b4.y; bvv[s + 2] = b4.z; bvv[s + 3] = b4.w;
  }
  // wave w owns heads h = 4w .. 4w+3; ug[h][e-slice] in registers
  float ug[4][16], Gu[4], Bu[4], A_l[4];
#pragma unroll
  for (int hh = 0; hh < 4; hh++) {
    int h = w * 4 + hh;
    const float* up = u_ws + (rr * 16 + h) * 1024 + e0;
    float gs = 0.f, bs = 0.f;
#pragma unroll
    for (int s = 0; s < 16; s += 4) {
      float4 uv = *(const float4*)(up + s);
      ug[hh][s + 0] = uv.x * gv[s + 0]; ug[hh][s + 1] = uv.y * gv[s + 1];
      ug[hh][s + 2] = uv.z * gv[s + 2]; ug[hh][s + 3] = uv.w * gv[s + 3];
      bs += uv.x * bvv[s + 0] + uv.y * bvv[s + 1] + uv.z * bvv[s + 2] + uv.w * bvv[s + 3];
      gs += ug[hh][s + 0] + ug[hh][s + 1] + ug[hh][s + 2] + ug[hh][s + 3];
    }
#pragma unroll
    for (int m = 32; m >= 1; m >>= 1) { gs += __shfl_xor(gs, m); bs += __shfl_xor(bs, m); }
    Gu[hh] = gs; Bu[hh] = bs;
    A_l[hh] = A_ws[rr * 16 + h];
  }

  // phase 1: scores (2 j-rows per iteration)
  for (int jj = 0; jj < 128; jj += 2) {
    const float* xp = rpe + (rr * 128 + jj) * 1024 + e0;
    float xa[16], xb[16];
#pragma unroll
    for (int s = 0; s < 16; s += 4) {
      float4 pa = *(const float4*)(xp + s);
      xa[s] = pa.x; xa[s + 1] = pa.y; xa[s + 2] = pa.z; xa[s + 3] = pa.w;
      float4 pb = *(const float4*)(xp + 1024 + s);
      xb[s] = pb.x; xb[s + 1] = pb.y; xb[s + 2] = pb.z; xb[s + 3] = pb.w;
    }
    float sxa = 0.f, sqa = 0.f, sxb = 0.f, sqb = 0.f;
#pragma unroll
    for (int s = 0; s < 16; s++) {
      sxa += xa[s]; sqa += xa[s] * xa[s];
      sxb += xb[s]; sqb += xb[s] * xb[s];
    }
    float aA[4] = {0, 0, 0, 0}, aB[4] = {0, 0, 0, 0};
#pragma unroll
    for (int hh = 0; hh < 4; hh++)
#pragma unroll
      for (int s = 0; s < 16; s++) {
        aA[hh] += xa[s] * ug[hh][s];
        aB[hh] += xb[s] * ug[hh][s];
      }
#pragma unroll
    for (int m = 32; m >= 1; m >>= 1) {
      sxa += __shfl_xor(sxa, m); sqa += __shfl_xor(sqa, m);
      sxb += __shfl_xor(sxb, m); sqb += __shfl_xor(sqb, m);
#pragma unroll
      for (int hh = 0; hh < 4; hh++) {
        aA[hh] += __shfl_xor(aA[hh], m);
        aB[hh] += __shfl_xor(aB[hh], m);
      }
    }
    float muA = sxa * (1.f / 1024.f), muB = sxb * (1.f / 1024.f);
    float rA = rsqrtf(fmaxf(sqa * (1.f / 1024.f) - muA * muA, 0.f) + 1e-5f);
    float rB = rsqrtf(fmaxf(sqb * (1.f / 1024.f) - muB * muB, 0.f) + 1e-5f);
    if (lane == 0) {
#pragma unroll
      for (int hh = 0; hh < 4; hh++) {
        sbuf[w * 4 + hh][jj]     = A_l[hh] + rA * (aA[hh] - muA * Gu[hh]) + Bu[hh];
        sbuf[w * 4 + hh][jj + 1] = A_l[hh] + rB * (aB[hh] - muB * Gu[hh]) + Bu[hh];
      }
      if (w == 0) { muS[jj] = muA; rsS[jj] = rA; muS[jj + 1] = muB; rsS[jj + 1] = rB; }
    }
  }
  __syncthreads();

  // phase 1.5: per-h local max / sumexp; sbuf <- p2 = exp(s-M_loc)*rstd_j
  {
    int h = tid >> 4, t16 = tid & 15;
    float m = -1e30f;
#pragma unroll
    for (int k = 0; k < 8; k++) m = fmaxf(m, sbuf[h][t16 + k * 16]);
#pragma unroll
    for (int mk = 8; mk >= 1; mk >>= 1) m = fmaxf(m, __shfl_xor(m, mk, 16));
    float z = 0.f, c1 = 0.f;
#pragma unroll
    for (int k = 0; k < 8; k++) {
      int j = t16 + k * 16;
      float p = expf(sbuf[h][j] - m);
      z += p;
      float p2 = p * rsS[j];
      c1 += p2 * muS[j];
      sbuf[h][j] = p2;
    }
#pragma unroll
    for (int mk = 8; mk >= 1; mk >>= 1) { z += __shfl_xor(z, mk, 16); c1 += __shfl_xor(c1, mk, 16); }
    if (t16 == 0) {
      M_ws[rr * 16 + h] = m; Z_ws[rr * 16 + h] = z;
      ZhS[h] = z; C1S[h] = c1;
    }
  }
  __syncthreads();

  // phase 2: W2[h,e] = sum_j p2[h,j] * x[j,e];  w_un = g*(W2-C1) + b*Z_loc
  {
    int e0b = tid * 4;
    float4 g4 = *(const float4*)(lng + e0b);
    float4 b4 = *(const float4*)(lnb + e0b);
    float acc[64];
#pragma unroll
    for (int i = 0; i < 64; i++) acc[i] = 0.f;
    for (int j = 0; j < 128; j++) {
      float4 x4 = *(const float4*)(rpe + (rr * 128 + j) * 1024 + e0b);
#pragma unroll
      for (int h = 0; h < 16; h++) {
        float pv = sbuf[h][j];
        acc[h * 4 + 0] += pv * x4.x;
        acc[h * 4 + 1] += pv * x4.y;
        acc[h * 4 + 2] += pv * x4.z;
        acc[h * 4 + 3] += pv * x4.w;
      }
    }
#pragma unroll
    for (int h = 0; h < 16; h++) {
      float4 o;
      o.x = g4.x * (acc[h * 4 + 0] - C1S[h]) + b4.x * ZhS[h];
      o.y = g4.y * (acc[h * 4 + 1] - C1S[h]) + b4.y * ZhS[h];
      o.z = g4.z * (acc[h * 4 + 2] - C1S[h]) + b4.z * ZhS[h];
      o.w = g4.w * (acc[h * 4 + 3] - C1S[h]) + b4.w * ZhS[h];
      *(float4*)(w_ws + (rr * 16 + h) * 1024 + e0b) = o;
    }
  }
}

// ---------------------------------------------------------------------------
// K3: global softmax combine over i: scale[r,h] = exp(M_loc - M)/Z
__global__ __launch_bounds__(256) void k_comb(
    const float* __restrict__ M_ws, const float* __restrict__ Z_ws, float* __restrict__ sc_ws)
{
  __shared__ float Mg[32], Zg[32];
  int tid = threadIdx.x;
  if (tid < 32) {
    int b = tid >> 4, h = tid & 15;
    float m = -1e30f;
    for (int i = 0; i < 128; i++) m = fmaxf(m, M_ws[((b << 7) + i) * 16 + h]);
    float z = 0.f;
    for (int i = 0; i < 128; i++) {
      int idx = ((b << 7) + i) * 16 + h;
      z += Z_ws[idx] * expf(M_ws[idx] - m);
    }
    Mg[tid] = m; Zg[tid] = z;
  }
  __syncthreads();
  for (int idx = tid; idx < 4096; idx += 256) {
    int r = idx >> 4, h = idx & 15, b = r >> 7;
    sc_ws[idx] = expf(M_ws[idx] - Mg[b * 16 + h]) / Zg[b * 16 + h];
  }
}

// ---------------------------------------------------------------------------
// K4: qv[r, h*64+d] = scale*(Z_loc*(v[r,g*64+d]+brv) + w_un[r,h,:]·Wrv[:,g*64+d])
__global__ __launch_bounds__(256) void k_qv(
    const float* __restrict__ w_ws, const float* __restrict__ v_ws,
    const float* __restrict__ Wrv, const float* __restrict__ brv,
    const float* __restrict__ Z_ws, const float* __restrict__ sc_ws,
    float* __restrict__ qv_ws)
{
  __shared__ float wtile[16][1024];  // 64 KB
  int rr = blockIdx.x, tid = threadIdx.x;
  for (int f = tid; f < 16 * 256; f += 256) {
    int h = f >> 8, c4 = f & 255;
    *(float4*)&wtile[h][c4 * 4] = *(const float4*)(w_ws + (rr * 16 + h) * 1024 + c4 * 4);
  }
  __syncthreads();
  for (int m = 0; m < 2; m++) {
    int col = tid + 256 * m;        // 0..511  (g*64+d), g uniform per wave
    int g = col >> 6, d = col & 63;
    float a0 = 0.f, a1 = 0.f;
    for (int e = 0; e < 1024; e += 2) {
      float w0 = Wrv[e * 512 + col];
      float w1 = Wrv[(e + 1) * 512 + col];
      float2 t0 = *(const float2*)&wtile[g * 2 + 0][e];
      float2 t1 = *(const float2*)&wtile[g * 2 + 1][e];
      a0 += t0.x * w0 + t0.y * w1;
      a1 += t1.x * w0 + t1.y * w1;
    }
    float vb = v_ws[rr * 512 + col] + brv[col];
    int h0 = g * 2, h1 = g * 2 + 1;
    qv_ws[rr * 1024 + h0 * 64 + d] = sc_ws[rr * 16 + h0] * (Z_ws[rr * 16 + h0] * vb + a0);
    qv_ws[rr * 1024 + h1 * 64 + d] = sc_ws[rr * 16 + h1] * (Z_ws[rr * 16 + h1] * vb + a1);
  }
}

// ---------------------------------------------------------------------------
// K5: out = qv @ Wo + bo  (f32 out)
__global__ __launch_bounds__(256) void k_out(
    const float* __restrict__ qv_ws, const float* __restrict__ Wo, const float* __restrict__ bo,
    float* __restrict__ out)
{
  __shared__ float qs[16][1024];   // 64 KB
  int ct = blockIdx.x, rt = blockIdx.y, tid = threadIdx.x;
  int row0 = rt * 16, c0 = ct * 128;
  for (int f = tid; f < 16 * 256; f += 256) {
    int rr = f >> 8, c4 = f & 255;
    *(float4*)&qs[rr][c4 * 4] = *(const float4*)(qv_ws + (row0 + rr) * 1024 + c4 * 4);
  }
  __syncthreads();
  int cl = tid & 127, rs = tid >> 7;
  int col = c0 + cl;
  float acc[8] = {0, 0, 0, 0, 0, 0, 0, 0};
  for (int e = 0; e < 1024; e += 2) {
    float w0 = Wo[e * 1024 + col];
    float w1 = Wo[(e + 1) * 1024 + col];
#pragma unroll
    for (int r = 0; r < 8; r++) {
      float2 q2 = *(const float2*)&qs[rs * 8 + r][e];
      acc[r] += q2.x * w0 + q2.y * w1;
    }
  }
  float bb = bo[col];
#pragma unroll
  for (int r = 0; r < 8; r++)
    out[(row0 + rs * 8 + r) * 1024 + col] = acc[r] + bb;
}

// ---------------------------------------------------------------------------
extern "C" void kernel_launch(void* const* d_in, const int* in_sizes, int n_in,
                              void* d_out, int out_size, void* d_ws, size_t ws_size,
                              hipStream_t stream) {
  (void)in_sizes; (void)n_in; (void)out_size; (void)ws_size;
  const float* Q   = (const float*)d_in[0];
  const float* K   = (const float*)d_in[1];
  const float* V   = (const float*)d_in[2];
  const float* rpe = (const float*)d_in[3];
  const float* lng = (const float*)d_in[4];
  const float* lnb = (const float*)d_in[5];
  const float* Wq  = (const float*)d_in[6];
  const float* bq  = (const float*)d_in[7];
  const float* Wk  = (const float*)d_in[8];
  const float* bk  = (const float*)d_in[9];
  const float* Wv  = (const float*)d_in[10];
  const float* bv  = (const float*)d_in[11];
  const float* Wrk = (const float*)d_in[12];
  const float* brk = (const float*)d_in[13];
  const float* Wrv = (const float*)d_in[14];
  const float* brv = (const float*)d_in[15];
  const float* Wo  = (const float*)d_in[16];
  const float* bo  = (const float*)d_in[17];
  float* out = (float*)d_out;

  float* ws    = (float*)d_ws;
  float* q_ws  = ws;                   // 262144
  float* k_ws  = q_ws + 262144;        // 131072
  float* v_ws  = k_ws + 131072;        // 131072
  float* u_ws  = v_ws + 131072;        // 4194304
  float* A_ws  = u_ws + 4194304;       // 4096
  float* M_ws  = A_ws + 4096;          // 4096
  float* Z_ws  = M_ws + 4096;          // 4096
  float* sc_ws = Z_ws + 4096;          // 4096
  float* w_ws  = sc_ws + 4096;         // 4194304
  float* qv_ws = w_ws + 4194304;       // 262144  (total ~36.8 MB)

  k_qkv<<<dim3(16, 16), 256, 0, stream>>>(Q, K, V, Wq, bq, Wk, bk, Wv, bv, q_ws, k_ws, v_ws);
  k_base<<<16, 256, 0, stream>>>(q_ws, k_ws, brk, A_ws);
  k_uproj<<<dim3(8, 32), 256, 0, stream>>>(q_ws, Wrk, u_ws);
  k_attn<<<256, 256, 0, stream>>>(rpe, lng, lnb, u_ws, A_ws, M_ws, Z_ws, w_ws);
  k_comb<<<1, 256, 0, stream>>>(M_ws, Z_ws, sc_ws);
  k_qv<<<256, 256, 0, stream>>>(w_ws, v_ws, Wrv, brv, Z_ws, sc_ws, qv_ws);
  k_out<<<dim3(8, 16), 256, 0, stream>>>(qv_ws, Wo, bo, out);
}

// Round 3
// 609.032 us; speedup vs baseline: 1.1423x; 1.1423x over previous
//
#include <hip/hip_runtime.h>

// B=2, L=128, E=1024, H=16, G=8, D=64, R=2. rows rr = b*128+i in [0,256).
// All inputs/outputs float32.

// ---------------------------------------------------------------------------
// K0: seed biases / zeros. grid 256 (rr), 256 thr.
__global__ __launch_bounds__(256) void k_zero(
    const float* __restrict__ bq, const float* __restrict__ bk, const float* __restrict__ bv,
    const float* __restrict__ bo,
    float* __restrict__ q_ws, float* __restrict__ k_ws, float* __restrict__ v_ws,
    float* __restrict__ qv_ws, float* __restrict__ out)
{
  int rr = blockIdx.x, tid = threadIdx.x;
#pragma unroll
  for (int s = 0; s < 4; s++) {
    int i = tid + s * 256;
    q_ws[rr * 1024 + i] = bq[i];
    qv_ws[rr * 1024 + i] = 0.f;
    out[rr * 1024 + i] = bo[i];
  }
#pragma unroll
  for (int s = 0; s < 2; s++) {
    int i = tid + s * 256;
    k_ws[rr * 512 + i] = bk[i];
    v_ws[rr * 512 + i] = bv[i];
  }
}

// ---------------------------------------------------------------------------
// K1: q/k/v projections, K-split with atomic accumulate.
// grid (8 ct, 32 rt, 2 es), 256 thr. Block: 8 rows x 256 cols x 512 e-range.
__global__ __launch_bounds__(256) void k_qkv(
    const float* __restrict__ Q, const float* __restrict__ K, const float* __restrict__ V,
    const float* __restrict__ Wq, const float* __restrict__ Wk, const float* __restrict__ Wv,
    float* __restrict__ q_ws, float* __restrict__ k_ws, float* __restrict__ v_ws)
{
  __shared__ float xs[8][512];
  int ct = blockIdx.x, rt = blockIdx.y, es = blockIdx.z, tid = threadIdx.x;
  const float* X; const float* W; float* out; int ldW, ldO, c0;
  if (ct < 4)      { X = Q; W = Wq; out = q_ws; ldW = 1024; ldO = 1024; c0 = ct * 256; }
  else if (ct < 6) { X = K; W = Wk; out = k_ws; ldW = 512;  ldO = 512;  c0 = (ct - 4) * 256; }
  else             { X = V; W = Wv; out = v_ws; ldW = 512;  ldO = 512;  c0 = (ct - 6) * 256; }
  int row0 = rt * 8, e0 = es * 512;
  for (int f = tid; f < 1024; f += 256) {
    int r = f >> 7, e4 = f & 127;
    *(float4*)&xs[r][e4 * 4] = *(const float4*)(X + (size_t)(row0 + r) * 1024 + e0 + e4 * 4);
  }
  __syncthreads();
  int cg = tid & 63, rs = tid >> 6;
  int c = c0 + cg * 4;
  float a0[4] = {0, 0, 0, 0}, a1[4] = {0, 0, 0, 0};
  for (int e = 0; e < 512; e++) {
    float4 w4 = *(const float4*)(W + (size_t)(e0 + e) * ldW + c);
    float x0 = xs[rs][e], x1 = xs[rs + 4][e];
    a0[0] += x0 * w4.x; a0[1] += x0 * w4.y; a0[2] += x0 * w4.z; a0[3] += x0 * w4.w;
    a1[0] += x1 * w4.x; a1[1] += x1 * w4.y; a1[2] += x1 * w4.z; a1[3] += x1 * w4.w;
  }
#pragma unroll
  for (int s = 0; s < 4; s++) {
    atomicAdd(out + (size_t)(row0 + rs) * ldO + c + s, a0[s]);
    atomicAdd(out + (size_t)(row0 + rs + 4) * ldO + c + s, a1[s]);
  }
}

// ---------------------------------------------------------------------------
// K2: A[r,h] = (q[r,h,:].(k[r,g,:]+brk[g,:])) / 8
__global__ __launch_bounds__(256) void k_base(
    const float* __restrict__ q_ws, const float* __restrict__ k_ws,
    const float* __restrict__ brk, float* __restrict__ A_ws)
{
  int t = blockIdx.x * 256 + threadIdx.x;  // 4096
  int r = t >> 4, h = t & 15, g = h >> 1;
  const float* qp = q_ws + r * 1024 + h * 64;
  const float* kp = k_ws + r * 512 + g * 64;
  const float* bp = brk + g * 64;
  float s = 0.f;
  for (int d = 0; d < 64; d++) s += qp[d] * (kp[d] + bp[d]);
  A_ws[t] = s * 0.125f;
}

// ---------------------------------------------------------------------------
// K3: ut[rr][e][h] = 0.125 * sum_d q[rr,h*64+d] * Wrk[e, g*64+d], g=h>>1.
// Per-g GEMM: rows m=(rr_local*2+hh) in [0,64), cols e-tile 128, K=64.
// grid (8 et, 8 rrt, 8 g), 256 thr.
__global__ __launch_bounds__(256) void k_uproj(
    const float* __restrict__ q_ws, const float* __restrict__ Wrk, float* __restrict__ ut_ws)
{
  __shared__ float wt[64][132];  // [d][e_local]
  __shared__ float qs[64][65];   // [m][d]
  int et = blockIdx.x, rrt = blockIdx.y, g = blockIdx.z, tid = threadIdx.x;
  int e0 = et * 128, rr0 = rrt * 32;
  // stage Wrk tile transposed
  for (int f = tid; f < 2048; f += 256) {
    int er = f >> 4, dq = f & 15;
    float4 p = *(const float4*)(Wrk + (size_t)(e0 + er) * 512 + g * 64 + dq * 4);
    wt[dq * 4 + 0][er] = p.x; wt[dq * 4 + 1][er] = p.y;
    wt[dq * 4 + 2][er] = p.z; wt[dq * 4 + 3][er] = p.w;
  }
  // stage q rows
  for (int f = tid; f < 1024; f += 256) {
    int m = f >> 4, dq = f & 15;
    int rr = rr0 + (m >> 1), h = g * 2 + (m & 1);
    float4 p = *(const float4*)(q_ws + (size_t)rr * 1024 + h * 64 + dq * 4);
    qs[m][dq * 4 + 0] = p.x; qs[m][dq * 4 + 1] = p.y;
    qs[m][dq * 4 + 2] = p.z; qs[m][dq * 4 + 3] = p.w;
  }
  __syncthreads();
  int eg = tid & 31, rs = tid >> 5;
  float acc[8][4];
#pragma unroll
  for (int i = 0; i < 8; i++)
#pragma unroll
    for (int s = 0; s < 4; s++) acc[i][s] = 0.f;
  for (int d = 0; d < 64; d++) {
    float4 wv = *(float4*)&wt[d][eg * 4];
#pragma unroll
    for (int i = 0; i < 8; i++) {
      float qv = qs[rs * 8 + i][d];
      acc[i][0] += qv * wv.x; acc[i][1] += qv * wv.y;
      acc[i][2] += qv * wv.z; acc[i][3] += qv * wv.w;
    }
  }
#pragma unroll
  for (int i = 0; i < 4; i++) {
    int m0 = rs * 8 + 2 * i;
    int rr = rr0 + (m0 >> 1);
#pragma unroll
    for (int s = 0; s < 4; s++) {
      int e = e0 + eg * 4 + s;
      float2 st;
      st.x = acc[2 * i][s] * 0.125f;
      st.y = acc[2 * i + 1][s] * 0.125f;
      *(float2*)(ut_ws + ((size_t)rr * 1024 + e) * 16 + g * 2) = st;
    }
  }
}

// ---------------------------------------------------------------------------
// K4: Gu[rr,h] = sum_e g_e*ut[rr,e,h];  S0[rr,h] = A[rr,h] + sum_e b_e*ut[rr,e,h]
// grid 256 (rr), 256 thr.
__global__ __launch_bounds__(256) void k_gub(
    const float* __restrict__ ut_ws, const float* __restrict__ lng, const float* __restrict__ lnb,
    const float* __restrict__ A_ws, float* __restrict__ Gu_ws, float* __restrict__ S0_ws)
{
  __shared__ float redG[64][16], redB[64][16];
  int rr = blockIdx.x, tid = threadIdx.x;
  int hq = tid & 3, es = tid >> 2;
  float4 gacc = {0, 0, 0, 0}, bacc = {0, 0, 0, 0};
  for (int k = 0; k < 16; k++) {
    int e = es * 16 + k;
    float4 u4 = *(const float4*)(ut_ws + ((size_t)rr * 1024 + e) * 16 + hq * 4);
    float ge = lng[e], be = lnb[e];
    gacc.x += ge * u4.x; gacc.y += ge * u4.y; gacc.z += ge * u4.z; gacc.w += ge * u4.w;
    bacc.x += be * u4.x; bacc.y += be * u4.y; bacc.z += be * u4.z; bacc.w += be * u4.w;
  }
  *(float4*)&redG[es][hq * 4] = gacc;
  *(float4*)&redB[es][hq * 4] = bacc;
  __syncthreads();
  if (tid < 16) {
    float gs = 0.f, bs = 0.f;
    for (int k = 0; k < 64; k++) { gs += redG[k][tid]; bs += redB[k][tid]; }
    Gu_ws[rr * 16 + tid] = gs;
    S0_ws[rr * 16 + tid] = A_ws[rr * 16 + tid] + bs;
  }
}

// ---------------------------------------------------------------------------
// K5: scores. grid (2 jt, 256 rr), 128 thr. Thread (jp,hg): 2 j x 4 h complete dots.
// s[j,h] = S0[h] + rstd_j*(x_j.(g*u_h) - mu_j*Gu[h])
__global__ __launch_bounds__(128) void k_attn_s(
    const float* __restrict__ rpe, const float* __restrict__ lng,
    const float* __restrict__ ut_ws, const float* __restrict__ Gu_ws,
    const float* __restrict__ S0_ws,
    float* __restrict__ s_ws, float* __restrict__ mu_ws, float* __restrict__ rs_ws)
{
  __shared__ float xs[64][132];   // 33.8 KB
  __shared__ float us[128][16];   // 8 KB
  int jt = blockIdx.x, rr = blockIdx.y, tid = threadIdx.x;
  int jp = tid >> 2, hg = tid & 3;
  int j0 = jp * 2;
  float acc0[4] = {0, 0, 0, 0}, acc1[4] = {0, 0, 0, 0};
  float sx0 = 0.f, sq0 = 0.f, sx1 = 0.f, sq1 = 0.f;

  for (int ec = 0; ec < 8; ec++) {
    __syncthreads();
    // stage u-chunk scaled by g: us[e][h] = g[e0+e]*ut[rr][e0+e][h]
    for (int f = tid; f < 512; f += 128) {
      int e = f >> 2, hq = f & 3;
      float4 u4 = *(const float4*)(ut_ws + ((size_t)rr * 1024 + ec * 128 + e) * 16 + hq * 4);
      float ge = lng[ec * 128 + e];
      u4.x *= ge; u4.y *= ge; u4.z *= ge; u4.w *= ge;
      *(float4*)&us[e][hq * 4] = u4;
    }
    // stage x-chunk: 64 j rows x 128 e
    for (int f = tid; f < 2048; f += 128) {
      int jr = f >> 5, e4 = f & 31;
      *(float4*)&xs[jr][e4 * 4] =
          *(const float4*)(rpe + ((size_t)(rr * 128 + jt * 64 + jr)) * 1024 + ec * 128 + e4 * 4);
    }
    __syncthreads();
    for (int e4 = 0; e4 < 32; e4++) {
      float4 xa = *(float4*)&xs[j0][e4 * 4];
      float4 xb = *(float4*)&xs[j0 + 1][e4 * 4];
      float4 u0 = *(float4*)&us[e4 * 4 + 0][hg * 4];
      float4 u1 = *(float4*)&us[e4 * 4 + 1][hg * 4];
      float4 u2 = *(float4*)&us[e4 * 4 + 2][hg * 4];
      float4 u3 = *(float4*)&us[e4 * 4 + 3][hg * 4];
      acc0[0] += xa.x * u0.x + xa.y * u1.x + xa.z * u2.x + xa.w * u3.x;
      acc0[1] += xa.x * u0.y + xa.y * u1.y + xa.z * u2.y + xa.w * u3.y;
      acc0[2] += xa.x * u0.z + xa.y * u1.z + xa.z * u2.z + xa.w * u3.z;
      acc0[3] += xa.x * u0.w + xa.y * u1.w + xa.z * u2.w + xa.w * u3.w;
      acc1[0] += xb.x * u0.x + xb.y * u1.x + xb.z * u2.x + xb.w * u3.x;
      acc1[1] += xb.x * u0.y + xb.y * u1.y + xb.z * u2.y + xb.w * u3.y;
      acc1[2] += xb.x * u0.z + xb.y * u1.z + xb.z * u2.z + xb.w * u3.z;
      acc1[3] += xb.x * u0.w + xb.y * u1.w + xb.z * u2.w + xb.w * u3.w;
      sx0 += xa.x + xa.y + xa.z + xa.w;
      sq0 += xa.x * xa.x + xa.y * xa.y + xa.z * xa.z + xa.w * xa.w;
      sx1 += xb.x + xb.y + xb.z + xb.w;
      sq1 += xb.x * xb.x + xb.y * xb.y + xb.z * xb.z + xb.w * xb.w;
    }
  }
  float4 Gu4 = *(const float4*)(Gu_ws + rr * 16 + hg * 4);
  float4 S04 = *(const float4*)(S0_ws + rr * 16 + hg * 4);
  float mu0 = sx0 * (1.f / 1024.f), mu1 = sx1 * (1.f / 1024.f);
  float r0 = rsqrtf(fmaxf(sq0 * (1.f / 1024.f) - mu0 * mu0, 0.f) + 1e-5f);
  float r1 = rsqrtf(fmaxf(sq1 * (1.f / 1024.f) - mu1 * mu1, 0.f) + 1e-5f);
  int jg0 = jt * 64 + j0;
  float4 s0, s1;
  s0.x = S04.x + r0 * (acc0[0] - mu0 * Gu4.x); s0.y = S04.y + r0 * (acc0[1] - mu0 * Gu4.y);
  s0.z = S04.z + r0 * (acc0[2] - mu0 * Gu4.z); s0.w = S04.w + r0 * (acc0[3] - mu0 * Gu4.w);
  s1.x = S04.x + r1 * (acc1[0] - mu1 * Gu4.x); s1.y = S04.y + r1 * (acc1[1] - mu1 * Gu4.y);
  s1.z = S04.z + r1 * (acc1[2] - mu1 * Gu4.z); s1.w = S04.w + r1 * (acc1[3] - mu1 * Gu4.w);
  *(float4*)(s_ws + ((size_t)rr * 128 + jg0) * 16 + hg * 4) = s0;
  *(float4*)(s_ws + ((size_t)rr * 128 + jg0 + 1) * 16 + hg * 4) = s1;
  if (hg == 0) {
    mu_ws[rr * 128 + jg0] = mu0; rs_ws[rr * 128 + jg0] = r0;
    mu_ws[rr * 128 + jg0 + 1] = mu1; rs_ws[rr * 128 + jg0 + 1] = r1;
  }
}

// ---------------------------------------------------------------------------
// K6: local softmax per (rr,h): M_loc, Z=sum exp, C1=sum p2*mu; p2 in-place over s.
// grid 256 (rr), 256 thr.
__global__ __launch_bounds__(256) void k_attn_p(
    const float* __restrict__ mu_ws, const float* __restrict__ rs_ws,
    float* __restrict__ s_ws,  // in: scores, out: p2
    float* __restrict__ M_ws, float* __restrict__ Z_ws, float* __restrict__ C1_ws)
{
  int rr = blockIdx.x, tid = threadIdx.x;
  int h = tid >> 4, jl = tid & 15;
  float sv[8];
  float m = -1e30f;
#pragma unroll
  for (int k = 0; k < 8; k++) {
    int j = jl + k * 16;
    sv[k] = s_ws[((size_t)rr * 128 + j) * 16 + h];
    m = fmaxf(m, sv[k]);
  }
#pragma unroll
  for (int mk = 8; mk >= 1; mk >>= 1) m = fmaxf(m, __shfl_xor(m, mk, 16));
  float z = 0.f, c1 = 0.f;
#pragma unroll
  for (int k = 0; k < 8; k++) {
    int j = jl + k * 16;
    float p = expf(sv[k] - m);
    z += p;
    float p2 = p * rs_ws[rr * 128 + j];
    c1 += p2 * mu_ws[rr * 128 + j];
    s_ws[((size_t)rr * 128 + j) * 16 + h] = p2;
  }
#pragma unroll
  for (int mk = 8; mk >= 1; mk >>= 1) { z += __shfl_xor(z, mk, 16); c1 += __shfl_xor(c1, mk, 16); }
  if (jl == 0) {
    M_ws[rr * 16 + h] = m; Z_ws[rr * 16 + h] = z; C1_ws[rr * 16 + h] = c1;
  }
}

// ---------------------------------------------------------------------------
// K7: global softmax combine: sc[r,h] = exp(M_loc - M_glob)/Z_glob
__global__ __launch_bounds__(256) void k_comb(
    const float* __restrict__ M_ws, const float* __restrict__ Z_ws, float* __restrict__ sc_ws)
{
  __shared__ float Mg[32], Zg[32];
  int tid = threadIdx.x;
  if (tid < 32) {
    int b = tid >> 4, h = tid & 15;
    float m = -1e30f;
    for (int i = 0; i < 128; i++) m = fmaxf(m, M_ws[((b << 7) + i) * 16 + h]);
    float z = 0.f;
    for (int i = 0; i < 128; i++) {
      int idx = ((b << 7) + i) * 16 + h;
      z += Z_ws[idx] * expf(M_ws[idx] - m);
    }
    Mg[tid] = m; Zg[tid] = z;
  }
  __syncthreads();
  for (int idx = tid; idx < 4096; idx += 256) {
    int r = idx >> 4, h = idx & 15, b = r >> 7;
    sc_ws[idx] = expf(M_ws[idx] - Mg[b * 16 + h]) / Zg[b * 16 + h];
  }
}

// ---------------------------------------------------------------------------
// K8: w_t[rr][e][h] = g_e*(sum_j p2[j,h]*x[j,e] - C1[h]) + b_e*Z[h]
// grid (4 et, 256 rr), 256 thr; thread owns one e-col, acc[16].
__global__ __launch_bounds__(256) void k_wun(
    const float* __restrict__ rpe, const float* __restrict__ lng, const float* __restrict__ lnb,
    const float* __restrict__ p2_ws,  // == s_ws (p2, layout [rr][j][16])
    const float* __restrict__ Z_ws, const float* __restrict__ C1_ws,
    float* __restrict__ w_ws)
{
  __shared__ float xs[32][260];   // 33.3 KB
  __shared__ float p2s[128][16];  // 8 KB
  __shared__ float C1S[16], ZS[16];
  int et = blockIdx.x, rr = blockIdx.y, tid = threadIdx.x;
  int e0 = et * 256;
  for (int f = tid; f < 512; f += 256) {
    int j = f >> 2, hq = f & 3;
    *(float4*)&p2s[j][hq * 4] = *(const float4*)(p2_ws + ((size_t)rr * 128 + j) * 16 + hq * 4);
  }
  if (tid < 16) { C1S[tid] = C1_ws[rr * 16 + tid]; ZS[tid] = Z_ws[rr * 16 + tid]; }
  float acc[16];
#pragma unroll
  for (int h = 0; h < 16; h++) acc[h] = 0.f;
  for (int jc = 0; jc < 4; jc++) {
    __syncthreads();
    for (int f = tid; f < 2048; f += 256) {
      int jr = f >> 6, e4 = f & 63;
      *(float4*)&xs[jr][e4 * 4] =
          *(const float4*)(rpe + ((size_t)(rr * 128 + jc * 32 + jr)) * 1024 + e0 + e4 * 4);
    }
    __syncthreads();
    for (int j = 0; j < 32; j++) {
      float x = xs[j][tid];
      float4 p0 = *(float4*)&p2s[jc * 32 + j][0];
      float4 p1 = *(float4*)&p2s[jc * 32 + j][4];
      float4 p2 = *(float4*)&p2s[jc * 32 + j][8];
      float4 p3 = *(float4*)&p2s[jc * 32 + j][12];
      acc[0] += x * p0.x; acc[1] += x * p0.y; acc[2] += x * p0.z; acc[3] += x * p0.w;
      acc[4] += x * p1.x; acc[5] += x * p1.y; acc[6] += x * p1.z; acc[7] += x * p1.w;
      acc[8] += x * p2.x; acc[9] += x * p2.y; acc[10] += x * p2.z; acc[11] += x * p2.w;
      acc[12] += x * p3.x; acc[13] += x * p3.y; acc[14] += x * p3.z; acc[15] += x * p3.w;
    }
  }
  int e = e0 + tid;
  float ge = lng[e], be = lnb[e];
  float* wp = w_ws + ((size_t)rr * 1024 + e) * 16;
#pragma unroll
  for (int hq = 0; hq < 4; hq++) {
    float4 o;
    o.x = ge * (acc[hq * 4 + 0] - C1S[hq * 4 + 0]) + be * ZS[hq * 4 + 0];
    o.y = ge * (acc[hq * 4 + 1] - C1S[hq * 4 + 1]) + be * ZS[hq * 4 + 1];
    o.z = ge * (acc[hq * 4 + 2] - C1S[hq * 4 + 2]) + be * ZS[hq * 4 + 2];
    o.w = ge * (acc[hq * 4 + 3] - C1S[hq * 4 + 3]) + be * ZS[hq * 4 + 3];
    *(float4*)(wp + hq * 4) = o;
  }
}

// ---------------------------------------------------------------------------
// K9: S[rr][h*64+d] += sum_e w_t[rr][e][h]*Wrv[e][g*64+d]  (atomic, e-split)
// grid (4 ec, 128 rp), 256 thr. Block: 2 rr, e-chunk 256, all 512 cols.
__global__ __launch_bounds__(256) void k_qv(
    const float* __restrict__ w_ws, const float* __restrict__ Wrv,
    float* __restrict__ qv_ws)
{
  __shared__ float wch[2][256][16];  // 32 KB
  int ec = blockIdx.x, rp = blockIdx.y, tid = threadIdx.x;
  int e0 = ec * 256, rr0 = rp * 2;
  for (int f = tid; f < 2048; f += 256) {
    int r2 = f >> 10, rem = f & 1023;
    int e = rem >> 2, hq = rem & 3;
    *(float4*)&wch[r2][e][hq * 4] =
        *(const float4*)(w_ws + ((size_t)(rr0 + r2) * 1024 + e0 + e) * 16 + hq * 4);
  }
  __syncthreads();
  int cg = tid & 127, es2 = tid >> 7;
  int c = cg * 4, g = cg >> 4, h0 = g * 2, dloc = (cg & 15) * 4;
  float a[2][2][4];
#pragma unroll
  for (int r = 0; r < 2; r++)
#pragma unroll
    for (int hh = 0; hh < 2; hh++)
#pragma unroll
      for (int s = 0; s < 4; s++) a[r][hh][s] = 0.f;
  for (int ei = 0; ei < 128; ei++) {
    int e = es2 * 128 + ei;
    float4 wv = *(const float4*)(Wrv + (size_t)(e0 + e) * 512 + c);
    float2 w0 = *(float2*)&wch[0][e][h0];
    float2 w1 = *(float2*)&wch[1][e][h0];
    a[0][0][0] += w0.x * wv.x; a[0][0][1] += w0.x * wv.y; a[0][0][2] += w0.x * wv.z; a[0][0][3] += w0.x * wv.w;
    a[0][1][0] += w0.y * wv.x; a[0][1][1] += w0.y * wv.y; a[0][1][2] += w0.y * wv.z; a[0][1][3] += w0.y * wv.w;
    a[1][0][0] += w1.x * wv.x; a[1][0][1] += w1.x * wv.y; a[1][0][2] += w1.x * wv.z; a[1][0][3] += w1.x * wv.w;
    a[1][1][0] += w1.y * wv.x; a[1][1][1] += w1.y * wv.y; a[1][1][2] += w1.y * wv.z; a[1][1][3] += w1.y * wv.w;
  }
#pragma unroll
  for (int r = 0; r < 2; r++)
#pragma unroll
    for (int hh = 0; hh < 2; hh++)
#pragma unroll
      for (int s = 0; s < 4; s++)
        atomicAdd(qv_ws + (size_t)(rr0 + r) * 1024 + (h0 + hh) * 64 + dloc + s, a[r][hh][s]);
}

// ---------------------------------------------------------------------------
// K10: out += qveff @ Wo, where qveff[r][e] = sc[r,h]*(Z[r,h]*(v[r,gd]+brv[gd]) + qv_ws[r][e])
// grid (4 ct, 32 rt, 2 es), 256 thr. out pre-seeded with bo.
__global__ __launch_bounds__(256) void k_out(
    const float* __restrict__ qv_ws, const float* __restrict__ v_ws,
    const float* __restrict__ brv, const float* __restrict__ Z_ws,
    const float* __restrict__ sc_ws, const float* __restrict__ Wo,
    float* __restrict__ out)
{
  __shared__ float xs[8][512];
  int ct = blockIdx.x, rt = blockIdx.y, es = blockIdx.z, tid = threadIdx.x;
  int row0 = rt * 8, e0 = es * 512, c0 = ct * 256;
  for (int f = tid; f < 4096; f += 256) {
    int r = f >> 9, ei = f & 511;
    int e = e0 + ei, row = row0 + r;
    int h = e >> 6, gg = h >> 1, dl = e & 63;
    float vb = v_ws[row * 512 + gg * 64 + dl] + brv[gg * 64 + dl];
    float val = sc_ws[row * 16 + h] * (Z_ws[row * 16 + h] * vb + qv_ws[(size_t)row * 1024 + e]);
    xs[r][ei] = val;
  }
  __syncthreads();
  int cg = tid & 63, rs = tid >> 6;
  int c = c0 + cg * 4;
  float a0[4] = {0, 0, 0, 0}, a1[4] = {0, 0, 0, 0};
  for (int e = 0; e < 512; e++) {
    float4 w4 = *(const float4*)(Wo + (size_t)(e0 + e) * 1024 + c);
    float x0 = xs[rs][e], x1 = xs[rs + 4][e];
    a0[0] += x0 * w4.x; a0[1] += x0 * w4.y; a0[2] += x0 * w4.z; a0[3] += x0 * w4.w;
    a1[0] += x1 * w4.x; a1[1] += x1 * w4.y; a1[2] += x1 * w4.z; a1[3] += x1 * w4.w;
  }
#pragma unroll
  for (int s = 0; s < 4; s++) {
    atomicAdd(out + (size_t)(row0 + rs) * 1024 + c + s, a0[s]);
    atomicAdd(out + (size_t)(row0 + rs + 4) * 1024 + c + s, a1[s]);
  }
}

// ---------------------------------------------------------------------------
extern "C" void kernel_launch(void* const* d_in, const int* in_sizes, int n_in,
                              void* d_out, int out_size, void* d_ws, size_t ws_size,
                              hipStream_t stream) {
  (void)in_sizes; (void)n_in; (void)out_size; (void)ws_size;
  const float* Q   = (const float*)d_in[0];
  const float* K   = (const float*)d_in[1];
  const float* V   = (const float*)d_in[2];
  const float* rpe = (const float*)d_in[3];
  const float* lng = (const float*)d_in[4];
  const float* lnb = (const float*)d_in[5];
  const float* Wq  = (const float*)d_in[6];
  const float* bq  = (const float*)d_in[7];
  const float* Wk  = (const float*)d_in[8];
  const float* bk  = (const float*)d_in[9];
  const float* Wv  = (const float*)d_in[10];
  const float* bv  = (const float*)d_in[11];
  const float* Wrk = (const float*)d_in[12];
  const float* brk = (const float*)d_in[13];
  const float* Wrv = (const float*)d_in[14];
  const float* brv = (const float*)d_in[15];
  const float* Wo  = (const float*)d_in[16];
  const float* bo  = (const float*)d_in[17];
  float* out = (float*)d_out;

  float* ws    = (float*)d_ws;
  float* q_ws  = ws;                    // 262144
  float* k_ws  = q_ws + 262144;         // 131072
  float* v_ws  = k_ws + 131072;         // 131072
  float* ut_ws = v_ws + 131072;         // 4194304  (reused as w_ws after k_attn_s)
  float* A_ws  = ut_ws + 4194304;       // 4096
  float* S0_ws = A_ws + 4096;           // 4096
  float* Gu_ws = S0_ws + 4096;          // 4096
  float* s_ws  = Gu_ws + 4096;          // 524288   (scores, then p2 in-place)
  float* mu_ws = s_ws + 524288;         // 32768
  float* rs_ws = mu_ws + 32768;         // 32768
  float* M_ws  = rs_ws + 32768;         // 4096
  float* Z_ws  = M_ws + 4096;           // 4096
  float* C1_ws = Z_ws + 4096;           // 4096
  float* sc_ws = C1_ws + 4096;          // 4096
  float* qv_ws = sc_ws + 4096;          // 262144   total ~22.6 MB
  float* w_ws  = ut_ws;                 // reuse

  k_zero<<<256, 256, 0, stream>>>(bq, bk, bv, bo, q_ws, k_ws, v_ws, qv_ws, out);
  k_qkv<<<dim3(8, 32, 2), 256, 0, stream>>>(Q, K, V, Wq, Wk, Wv, q_ws, k_ws, v_ws);
  k_base<<<16, 256, 0, stream>>>(q_ws, k_ws, brk, A_ws);
  k_uproj<<<dim3(8, 8, 8), 256, 0, stream>>>(q_ws, Wrk, ut_ws);
  k_gub<<<256, 256, 0, stream>>>(ut_ws, lng, lnb, A_ws, Gu_ws, S0_ws);
  k_attn_s<<<dim3(2, 256), 128, 0, stream>>>(rpe, lng, ut_ws, Gu_ws, S0_ws, s_ws, mu_ws, rs_ws);
  k_attn_p<<<256, 256, 0, stream>>>(mu_ws, rs_ws, s_ws, M_ws, Z_ws, C1_ws);
  k_comb<<<1, 256, 0, stream>>>(M_ws, Z_ws, sc_ws);
  k_wun<<<dim3(4, 256), 256, 0, stream>>>(rpe, lng, lnb, s_ws, Z_ws, C1_ws, w_ws);
  k_qv<<<dim3(4, 128), 256, 0, stream>>>(w_ws, Wrv, qv_ws);
  k_out<<<dim3(4, 32, 2), 256, 0, stream>>>(qv_ws, v_ws, brv, Z_ws, sc_ws, Wo, out);
}

// Round 4
// 535.402 us; speedup vs baseline: 1.2994x; 1.1375x over previous
//
#include <hip/hip_runtime.h>

// B=2, L=128, E=1024, H=16, G=8, D=64, R=2. rows rr = b*128+i in [0,256).
// All inputs/outputs float32.

// ---------------------------------------------------------------------------
// K0: seed biases / zeros. grid 256, 256 thr.
__global__ __launch_bounds__(256) void k_zero(
    const float* __restrict__ bq, const float* __restrict__ bk, const float* __restrict__ bv,
    const float* __restrict__ bo,
    float* __restrict__ q_ws, float* __restrict__ k_ws, float* __restrict__ v_ws,
    float* __restrict__ qv_ws, float* __restrict__ out, float* __restrict__ Gu_ws)
{
  int rr = blockIdx.x, tid = threadIdx.x;
#pragma unroll
  for (int s = 0; s < 4; s++) {
    int i = tid + s * 256;
    q_ws[rr * 1024 + i] = bq[i];
    qv_ws[rr * 1024 + i] = 0.f;
    out[rr * 1024 + i] = bo[i];
  }
#pragma unroll
  for (int s = 0; s < 2; s++) {
    int i = tid + s * 256;
    k_ws[rr * 512 + i] = bk[i];
    v_ws[rr * 512 + i] = bv[i];
  }
  int t = rr * 256 + tid;
  if (t < 4096) Gu_ws[t] = 0.f;
}

// ---------------------------------------------------------------------------
// K1: q/k/v projections, K-split (es=4) with atomic accumulate.
// grid (8 ct, 32 rt, 4 es), 256 thr.
__global__ __launch_bounds__(256) void k_qkv(
    const float* __restrict__ Q, const float* __restrict__ K, const float* __restrict__ V,
    const float* __restrict__ Wq, const float* __restrict__ Wk, const float* __restrict__ Wv,
    float* __restrict__ q_ws, float* __restrict__ k_ws, float* __restrict__ v_ws)
{
  __shared__ float xs[8][256];
  int ct = blockIdx.x, rt = blockIdx.y, es = blockIdx.z, tid = threadIdx.x;
  const float* X; const float* W; float* out; int ldW, ldO, c0;
  if (ct < 4)      { X = Q; W = Wq; out = q_ws; ldW = 1024; ldO = 1024; c0 = ct * 256; }
  else if (ct < 6) { X = K; W = Wk; out = k_ws; ldW = 512;  ldO = 512;  c0 = (ct - 4) * 256; }
  else             { X = V; W = Wv; out = v_ws; ldW = 512;  ldO = 512;  c0 = (ct - 6) * 256; }
  int row0 = rt * 8, e0 = es * 256;
  for (int f = tid; f < 512; f += 256) {
    int r = f >> 6, e4 = f & 63;
    *(float4*)&xs[r][e4 * 4] = *(const float4*)(X + (size_t)(row0 + r) * 1024 + e0 + e4 * 4);
  }
  __syncthreads();
  int cg = tid & 63, rs = tid >> 6;
  int c = c0 + cg * 4;
  float a0[4] = {0, 0, 0, 0}, a1[4] = {0, 0, 0, 0};
  for (int e = 0; e < 256; e++) {
    float4 w4 = *(const float4*)(W + (size_t)(e0 + e) * ldW + c);
    float x0 = xs[rs][e], x1 = xs[rs + 4][e];
    a0[0] += x0 * w4.x; a0[1] += x0 * w4.y; a0[2] += x0 * w4.z; a0[3] += x0 * w4.w;
    a1[0] += x1 * w4.x; a1[1] += x1 * w4.y; a1[2] += x1 * w4.z; a1[3] += x1 * w4.w;
  }
#pragma unroll
  for (int s = 0; s < 4; s++) {
    atomicAdd(out + (size_t)(row0 + rs) * ldO + c + s, a0[s]);
    atomicAdd(out + (size_t)(row0 + rs + 4) * ldO + c + s, a1[s]);
  }
}

// ---------------------------------------------------------------------------
// K2: S0[r,h] = A = (q[r,h,:].(k[r,g,:]+brk[g,:])) / 8   (Bu added later by k_uproj)
__global__ __launch_bounds__(256) void k_base(
    const float* __restrict__ q_ws, const float* __restrict__ k_ws,
    const float* __restrict__ brk, float* __restrict__ S0_ws)
{
  int t = blockIdx.x * 256 + threadIdx.x;  // 4096
  int r = t >> 4, h = t & 15, g = h >> 1;
  const float* qp = q_ws + r * 1024 + h * 64;
  const float* kp = k_ws + r * 512 + g * 64;
  const float* bp = brk + g * 64;
  float s = 0.f;
  for (int d = 0; d < 64; d++) s += qp[d] * (kp[d] + bp[d]);
  S0_ws[t] = s * 0.125f;
}

// ---------------------------------------------------------------------------
// K3: ut[rr][e][h] = 0.125 * sum_d q[rr,h*64+d] * Wrk[e, g*64+d], g=h>>1.
// Also accumulates Gu[rr,h] += sum_e g_e*ut, S0[rr,h] += sum_e b_e*ut (atomics).
// grid (8 et, 8 rrt, 8 g), 256 thr.
__global__ __launch_bounds__(256) void k_uproj(
    const float* __restrict__ q_ws, const float* __restrict__ Wrk,
    const float* __restrict__ lng, const float* __restrict__ lnb,
    float* __restrict__ ut_ws, float* __restrict__ Gu_ws, float* __restrict__ S0_ws)
{
  __shared__ float wt[64][132];  // [d][e_local]
  __shared__ float qs[64][65];   // [m][d]
  int et = blockIdx.x, rrt = blockIdx.y, g = blockIdx.z, tid = threadIdx.x;
  int e0 = et * 128, rr0 = rrt * 32;
  for (int f = tid; f < 2048; f += 256) {
    int er = f >> 4, dq = f & 15;
    float4 p = *(const float4*)(Wrk + (size_t)(e0 + er) * 512 + g * 64 + dq * 4);
    wt[dq * 4 + 0][er] = p.x; wt[dq * 4 + 1][er] = p.y;
    wt[dq * 4 + 2][er] = p.z; wt[dq * 4 + 3][er] = p.w;
  }
  for (int f = tid; f < 1024; f += 256) {
    int m = f >> 4, dq = f & 15;
    int rr = rr0 + (m >> 1), h = g * 2 + (m & 1);
    float4 p = *(const float4*)(q_ws + (size_t)rr * 1024 + h * 64 + dq * 4);
    qs[m][dq * 4 + 0] = p.x; qs[m][dq * 4 + 1] = p.y;
    qs[m][dq * 4 + 2] = p.z; qs[m][dq * 4 + 3] = p.w;
  }
  __syncthreads();
  int eg = tid & 31, rs = tid >> 5;
  float acc[8][4];
#pragma unroll
  for (int i = 0; i < 8; i++)
#pragma unroll
    for (int s = 0; s < 4; s++) acc[i][s] = 0.f;
  for (int d = 0; d < 64; d++) {
    float4 wv = *(float4*)&wt[d][eg * 4];
#pragma unroll
    for (int i = 0; i < 8; i++) {
      float qv = qs[rs * 8 + i][d];
      acc[i][0] += qv * wv.x; acc[i][1] += qv * wv.y;
      acc[i][2] += qv * wv.z; acc[i][3] += qv * wv.w;
    }
  }
  // store ut
#pragma unroll
  for (int i = 0; i < 4; i++) {
    int m0 = rs * 8 + 2 * i;
    int rr = rr0 + (m0 >> 1);
#pragma unroll
    for (int s = 0; s < 4; s++) {
      int e = e0 + eg * 4 + s;
      float2 st;
      st.x = acc[2 * i][s] * 0.125f;
      st.y = acc[2 * i + 1][s] * 0.125f;
      *(float2*)(ut_ws + ((size_t)rr * 1024 + e) * 16 + g * 2) = st;
    }
  }
  // fused Gu / Bu partial reduction over this block's 128-e tile
  float4 ge4 = *(const float4*)(lng + e0 + eg * 4);
  float4 be4 = *(const float4*)(lnb + e0 + eg * 4);
#pragma unroll
  for (int i = 0; i < 8; i++) {
    float pg = 0.125f * (ge4.x * acc[i][0] + ge4.y * acc[i][1] + ge4.z * acc[i][2] + ge4.w * acc[i][3]);
    float pb = 0.125f * (be4.x * acc[i][0] + be4.y * acc[i][1] + be4.z * acc[i][2] + be4.w * acc[i][3]);
#pragma unroll
    for (int mk = 16; mk >= 1; mk >>= 1) { pg += __shfl_xor(pg, mk); pb += __shfl_xor(pb, mk); }
    if (eg == 0) {
      int m = rs * 8 + i;
      int rr = rr0 + (m >> 1), h = g * 2 + (m & 1);
      atomicAdd(Gu_ws + rr * 16 + h, pg);
      atomicAdd(S0_ws + rr * 16 + h, pb);
    }
  }
}

// ---------------------------------------------------------------------------
// K4: scores. grid (4 jt, 256 rr), 128 thr.
// Thread (jp,hg,es2): 2 j x 4 h over 512-e half; es2 pair combined by shfl_xor(1).
// s[j,h] = S0[h] + rstd_j*(x_j.(g*u_h) - mu_j*Gu[h])
__global__ __launch_bounds__(128) void k_dotp(
    const float* __restrict__ rpe, const float* __restrict__ lng,
    const float* __restrict__ ut_ws, const float* __restrict__ Gu_ws,
    const float* __restrict__ S0_ws,
    float* __restrict__ s_ws, float* __restrict__ mu_ws, float* __restrict__ rs_ws)
{
  __shared__ float xs[32][140];   // e-half 0 at [0..63], half 1 at [68..131]
  __shared__ float us[128][16];
  int jt = blockIdx.x, rr = blockIdx.y, tid = threadIdx.x;
  int es2 = tid & 1, hg = (tid >> 1) & 3, jp = tid >> 3;
  int j0 = jp * 2;
  float acc0[4] = {0, 0, 0, 0}, acc1[4] = {0, 0, 0, 0};
  float sx0 = 0.f, sq0 = 0.f, sx1 = 0.f, sq1 = 0.f;

  for (int ec = 0; ec < 8; ec++) {
    __syncthreads();
    for (int f = tid; f < 512; f += 128) {
      int e = f >> 2, hq = f & 3;
      float4 u4 = *(const float4*)(ut_ws + ((size_t)rr * 1024 + ec * 128 + e) * 16 + hq * 4);
      float ge = lng[ec * 128 + e];
      u4.x *= ge; u4.y *= ge; u4.z *= ge; u4.w *= ge;
      *(float4*)&us[e][hq * 4] = u4;
    }
    for (int f = tid; f < 1024; f += 128) {
      int j = f >> 5, e4 = f & 31;
      int slot = (e4 < 16) ? e4 * 4 : e4 * 4 + 4;
      *(float4*)&xs[j][slot] =
          *(const float4*)(rpe + ((size_t)(rr * 128 + jt * 32 + j)) * 1024 + ec * 128 + e4 * 4);
    }
    __syncthreads();
    int ebase = es2 * 68, ubase = es2 * 64;
    for (int e4 = 0; e4 < 16; e4++) {
      float4 xa = *(float4*)&xs[j0][ebase + e4 * 4];
      float4 xb = *(float4*)&xs[j0 + 1][ebase + e4 * 4];
      float4 u0 = *(float4*)&us[ubase + e4 * 4 + 0][hg * 4];
      float4 u1 = *(float4*)&us[ubase + e4 * 4 + 1][hg * 4];
      float4 u2 = *(float4*)&us[ubase + e4 * 4 + 2][hg * 4];
      float4 u3 = *(float4*)&us[ubase + e4 * 4 + 3][hg * 4];
      acc0[0] += xa.x * u0.x + xa.y * u1.x + xa.z * u2.x + xa.w * u3.x;
      acc0[1] += xa.x * u0.y + xa.y * u1.y + xa.z * u2.y + xa.w * u3.y;
      acc0[2] += xa.x * u0.z + xa.y * u1.z + xa.z * u2.z + xa.w * u3.z;
      acc0[3] += xa.x * u0.w + xa.y * u1.w + xa.z * u2.w + xa.w * u3.w;
      acc1[0] += xb.x * u0.x + xb.y * u1.x + xb.z * u2.x + xb.w * u3.x;
      acc1[1] += xb.x * u0.y + xb.y * u1.y + xb.z * u2.y + xb.w * u3.y;
      acc1[2] += xb.x * u0.z + xb.y * u1.z + xb.z * u2.z + xb.w * u3.z;
      acc1[3] += xb.x * u0.w + xb.y * u1.w + xb.z * u2.w + xb.w * u3.w;
      sx0 += xa.x + xa.y + xa.z + xa.w;
      sq0 += xa.x * xa.x + xa.y * xa.y + xa.z * xa.z + xa.w * xa.w;
      sx1 += xb.x + xb.y + xb.z + xb.w;
      sq1 += xb.x * xb.x + xb.y * xb.y + xb.z * xb.z + xb.w * xb.w;
    }
  }
  // combine es2 halves (partner lane = lane^1)
#pragma unroll
  for (int s = 0; s < 4; s++) {
    acc0[s] += __shfl_xor(acc0[s], 1);
    acc1[s] += __shfl_xor(acc1[s], 1);
  }
  sx0 += __shfl_xor(sx0, 1); sq0 += __shfl_xor(sq0, 1);
  sx1 += __shfl_xor(sx1, 1); sq1 += __shfl_xor(sq1, 1);

  float4 Gu4 = *(const float4*)(Gu_ws + rr * 16 + hg * 4);
  float4 S04 = *(const float4*)(S0_ws + rr * 16 + hg * 4);
  float mu0 = sx0 * (1.f / 1024.f), mu1 = sx1 * (1.f / 1024.f);
  float r0 = rsqrtf(fmaxf(sq0 * (1.f / 1024.f) - mu0 * mu0, 0.f) + 1e-5f);
  float r1 = rsqrtf(fmaxf(sq1 * (1.f / 1024.f) - mu1 * mu1, 0.f) + 1e-5f);
  int jg0 = jt * 32 + j0;
  if (es2 == 0) {
    float4 o0, o1;
    o0.x = S04.x + r0 * (acc0[0] - mu0 * Gu4.x); o0.y = S04.y + r0 * (acc0[1] - mu0 * Gu4.y);
    o0.z = S04.z + r0 * (acc0[2] - mu0 * Gu4.z); o0.w = S04.w + r0 * (acc0[3] - mu0 * Gu4.w);
    o1.x = S04.x + r1 * (acc1[0] - mu1 * Gu4.x); o1.y = S04.y + r1 * (acc1[1] - mu1 * Gu4.y);
    o1.z = S04.z + r1 * (acc1[2] - mu1 * Gu4.z); o1.w = S04.w + r1 * (acc1[3] - mu1 * Gu4.w);
    *(float4*)(s_ws + ((size_t)rr * 128 + jg0) * 16 + hg * 4) = o0;
    *(float4*)(s_ws + ((size_t)rr * 128 + jg0 + 1) * 16 + hg * 4) = o1;
    if (hg == 0) {
      mu_ws[rr * 128 + jg0] = mu0; rs_ws[rr * 128 + jg0] = r0;
      mu_ws[rr * 128 + jg0 + 1] = mu1; rs_ws[rr * 128 + jg0 + 1] = r1;
    }
  }
}

// ---------------------------------------------------------------------------
// K5: local softmax per (rr,h): M, Z, C1; p2 in-place. grid 256, 256 thr.
__global__ __launch_bounds__(256) void k_attn_p(
    const float* __restrict__ mu_ws, const float* __restrict__ rs_ws,
    float* __restrict__ s_ws,
    float* __restrict__ M_ws, float* __restrict__ Z_ws, float* __restrict__ C1_ws)
{
  int rr = blockIdx.x, tid = threadIdx.x;
  int h = tid >> 4, jl = tid & 15;
  float sv[8];
  float m = -1e30f;
#pragma unroll
  for (int k = 0; k < 8; k++) {
    int j = jl + k * 16;
    sv[k] = s_ws[((size_t)rr * 128 + j) * 16 + h];
    m = fmaxf(m, sv[k]);
  }
#pragma unroll
  for (int mk = 8; mk >= 1; mk >>= 1) m = fmaxf(m, __shfl_xor(m, mk, 16));
  float z = 0.f, c1 = 0.f;
#pragma unroll
  for (int k = 0; k < 8; k++) {
    int j = jl + k * 16;
    float p = expf(sv[k] - m);
    z += p;
    float p2 = p * rs_ws[rr * 128 + j];
    c1 += p2 * mu_ws[rr * 128 + j];
    s_ws[((size_t)rr * 128 + j) * 16 + h] = p2;
  }
#pragma unroll
  for (int mk = 8; mk >= 1; mk >>= 1) { z += __shfl_xor(z, mk, 16); c1 += __shfl_xor(c1, mk, 16); }
  if (jl == 0) {
    M_ws[rr * 16 + h] = m; Z_ws[rr * 16 + h] = z; C1_ws[rr * 16 + h] = c1;
  }
}

// ---------------------------------------------------------------------------
// K6: global softmax combine: sc[r,h] = exp(M_loc - M_glob)/Z_glob
__global__ __launch_bounds__(256) void k_comb(
    const float* __restrict__ M_ws, const float* __restrict__ Z_ws, float* __restrict__ sc_ws)
{
  __shared__ float Mg[32], Zg[32];
  int tid = threadIdx.x;
  if (tid < 32) {
    int b = tid >> 4, h = tid & 15;
    float m = -1e30f;
    for (int i = 0; i < 128; i++) m = fmaxf(m, M_ws[((b << 7) + i) * 16 + h]);
    float z = 0.f;
    for (int i = 0; i < 128; i++) {
      int idx = ((b << 7) + i) * 16 + h;
      z += Z_ws[idx] * expf(M_ws[idx] - m);
    }
    Mg[tid] = m; Zg[tid] = z;
  }
  __syncthreads();
  for (int idx = tid; idx < 4096; idx += 256) {
    int r = idx >> 4, h = idx & 15, b = r >> 7;
    sc_ws[idx] = expf(M_ws[idx] - Mg[b * 16 + h]) / Zg[b * 16 + h];
  }
}

// ---------------------------------------------------------------------------
// K7: w_t[rr][e][h] = g_e*(sum_j p2[j,h]*x[j,e] - C1[h]) + b_e*Z[h]
// grid (2 et, 256 rr), 256 thr. Thread owns 2 e-cols (acc[2][16]).
__global__ __launch_bounds__(256) void k_wun(
    const float* __restrict__ rpe, const float* __restrict__ lng, const float* __restrict__ lnb,
    const float* __restrict__ p2_ws,
    const float* __restrict__ Z_ws, const float* __restrict__ C1_ws,
    float* __restrict__ w_ws)
{
  __shared__ float xs[8][520];    // 16.6 KB
  __shared__ float p2s[128][16];  // 8 KB
  __shared__ float C1S[16], ZS[16];
  int et = blockIdx.x, rr = blockIdx.y, tid = threadIdx.x;
  int e0 = et * 512;
  for (int f = tid; f < 512; f += 256) {
    int j = f >> 2, hq = f & 3;
    *(float4*)&p2s[j][hq * 4] = *(const float4*)(p2_ws + ((size_t)rr * 128 + j) * 16 + hq * 4);
  }
  if (tid < 16) { C1S[tid] = C1_ws[rr * 16 + tid]; ZS[tid] = Z_ws[rr * 16 + tid]; }
  float acc[2][16];
#pragma unroll
  for (int c = 0; c < 2; c++)
#pragma unroll
    for (int h = 0; h < 16; h++) acc[c][h] = 0.f;
  for (int jc = 0; jc < 16; jc++) {
    __syncthreads();
    for (int f = tid; f < 1024; f += 256) {
      int j = f >> 7, e4 = f & 127;
      *(float4*)&xs[j][e4 * 4] =
          *(const float4*)(rpe + ((size_t)(rr * 128 + jc * 8 + j)) * 1024 + e0 + e4 * 4);
    }
    __syncthreads();
#pragma unroll
    for (int j = 0; j < 8; j++) {
      float2 x2 = *(float2*)&xs[j][tid * 2];
      float4 p0 = *(float4*)&p2s[jc * 8 + j][0];
      float4 p1 = *(float4*)&p2s[jc * 8 + j][4];
      float4 p2 = *(float4*)&p2s[jc * 8 + j][8];
      float4 p3 = *(float4*)&p2s[jc * 8 + j][12];
      acc[0][0] += x2.x * p0.x; acc[0][1] += x2.x * p0.y; acc[0][2] += x2.x * p0.z; acc[0][3] += x2.x * p0.w;
      acc[0][4] += x2.x * p1.x; acc[0][5] += x2.x * p1.y; acc[0][6] += x2.x * p1.z; acc[0][7] += x2.x * p1.w;
      acc[0][8] += x2.x * p2.x; acc[0][9] += x2.x * p2.y; acc[0][10] += x2.x * p2.z; acc[0][11] += x2.x * p2.w;
      acc[0][12] += x2.x * p3.x; acc[0][13] += x2.x * p3.y; acc[0][14] += x2.x * p3.z; acc[0][15] += x2.x * p3.w;
      acc[1][0] += x2.y * p0.x; acc[1][1] += x2.y * p0.y; acc[1][2] += x2.y * p0.z; acc[1][3] += x2.y * p0.w;
      acc[1][4] += x2.y * p1.x; acc[1][5] += x2.y * p1.y; acc[1][6] += x2.y * p1.z; acc[1][7] += x2.y * p1.w;
      acc[1][8] += x2.y * p2.x; acc[1][9] += x2.y * p2.y; acc[1][10] += x2.y * p2.z; acc[1][11] += x2.y * p2.w;
      acc[1][12] += x2.y * p3.x; acc[1][13] += x2.y * p3.y; acc[1][14] += x2.y * p3.z; acc[1][15] += x2.y * p3.w;
    }
  }
  int e = e0 + tid * 2;
#pragma unroll
  for (int c = 0; c < 2; c++) {
    float ge = lng[e + c], be = lnb[e + c];
    float* wp = w_ws + ((size_t)rr * 1024 + e + c) * 16;
#pragma unroll
    for (int hq = 0; hq < 4; hq++) {
      float4 o;
      o.x = ge * (acc[c][hq * 4 + 0] - C1S[hq * 4 + 0]) + be * ZS[hq * 4 + 0];
      o.y = ge * (acc[c][hq * 4 + 1] - C1S[hq * 4 + 1]) + be * ZS[hq * 4 + 1];
      o.z = ge * (acc[c][hq * 4 + 2] - C1S[hq * 4 + 2]) + be * ZS[hq * 4 + 2];
      o.w = ge * (acc[c][hq * 4 + 3] - C1S[hq * 4 + 3]) + be * ZS[hq * 4 + 3];
      *(float4*)(wp + hq * 4) = o;
    }
  }
}

// ---------------------------------------------------------------------------
// K8: qv[rr][h*64+d] += sum_e w_t[rr][e][h]*Wrv[e][g*64+d]  (atomic, e-split)
// grid (4 ec, 128 rp), 256 thr.
__global__ __launch_bounds__(256) void k_qv(
    const float* __restrict__ w_ws, const float* __restrict__ Wrv,
    float* __restrict__ qv_ws)
{
  __shared__ float wch[2][256][16];  // 32 KB
  int ec = blockIdx.x, rp = blockIdx.y, tid = threadIdx.x;
  int e0 = ec * 256, rr0 = rp * 2;
  for (int f = tid; f < 2048; f += 256) {
    int r2 = f >> 10, rem = f & 1023;
    int e = rem >> 2, hq = rem & 3;
    *(float4*)&wch[r2][e][hq * 4] =
        *(const float4*)(w_ws + ((size_t)(rr0 + r2) * 1024 + e0 + e) * 16 + hq * 4);
  }
  __syncthreads();
  int cg = tid & 127, es2 = tid >> 7;
  int c = cg * 4, g = cg >> 4, h0 = g * 2, dloc = (cg & 15) * 4;
  float a[2][2][4];
#pragma unroll
  for (int r = 0; r < 2; r++)
#pragma unroll
    for (int hh = 0; hh < 2; hh++)
#pragma unroll
      for (int s = 0; s < 4; s++) a[r][hh][s] = 0.f;
  for (int ei = 0; ei < 128; ei++) {
    int e = es2 * 128 + ei;
    float4 wv = *(const float4*)(Wrv + (size_t)(e0 + e) * 512 + c);
    float2 w0 = *(float2*)&wch[0][e][h0];
    float2 w1 = *(float2*)&wch[1][e][h0];
    a[0][0][0] += w0.x * wv.x; a[0][0][1] += w0.x * wv.y; a[0][0][2] += w0.x * wv.z; a[0][0][3] += w0.x * wv.w;
    a[0][1][0] += w0.y * wv.x; a[0][1][1] += w0.y * wv.y; a[0][1][2] += w0.y * wv.z; a[0][1][3] += w0.y * wv.w;
    a[1][0][0] += w1.x * wv.x; a[1][0][1] += w1.x * wv.y; a[1][0][2] += w1.x * wv.z; a[1][0][3] += w1.x * wv.w;
    a[1][1][0] += w1.y * wv.x; a[1][1][1] += w1.y * wv.y; a[1][1][2] += w1.y * wv.z; a[1][1][3] += w1.y * wv.w;
  }
#pragma unroll
  for (int r = 0; r < 2; r++)
#pragma unroll
    for (int hh = 0; hh < 2; hh++)
#pragma unroll
      for (int s = 0; s < 4; s++)
        atomicAdd(qv_ws + (size_t)(rr0 + r) * 1024 + (h0 + hh) * 64 + dloc + s, a[r][hh][s]);
}

// ---------------------------------------------------------------------------
// K9: out += qveff @ Wo, qveff[r][e] = sc[r,h]*(Z[r,h]*(v[r,gd]+brv[gd]) + qv_ws[r][e])
// grid (4 ct, 32 rt, 4 es), 256 thr. out pre-seeded with bo.
__global__ __launch_bounds__(256) void k_out(
    const float* __restrict__ qv_ws, const float* __restrict__ v_ws,
    const float* __restrict__ brv, const float* __restrict__ Z_ws,
    const float* __restrict__ sc_ws, const float* __restrict__ Wo,
    float* __restrict__ out)
{
  __shared__ float xs[8][256];
  int ct = blockIdx.x, rt = blockIdx.y, es = blockIdx.z, tid = threadIdx.x;
  int row0 = rt * 8, e0 = es * 256, c0 = ct * 256;
  for (int f = tid; f < 2048; f += 256) {
    int r = f >> 8, ei = f & 255;
    int e = e0 + ei, row = row0 + r;
    int h = e >> 6, gg = h >> 1, dl = e & 63;
    float vb = v_ws[row * 512 + gg * 64 + dl] + brv[gg * 64 + dl];
    xs[r][ei] = sc_ws[row * 16 + h] * (Z_ws[row * 16 + h] * vb + qv_ws[(size_t)row * 1024 + e]);
  }
  __syncthreads();
  int cg = tid & 63, rs = tid >> 6;
  int c = c0 + cg * 4;
  float a0[4] = {0, 0, 0, 0}, a1[4] = {0, 0, 0, 0};
  for (int e = 0; e < 256; e++) {
    float4 w4 = *(const float4*)(Wo + (size_t)(e0 + e) * 1024 + c);
    float x0 = xs[rs][e], x1 = xs[rs + 4][e];
    a0[0] += x0 * w4.x; a0[1] += x0 * w4.y; a0[2] += x0 * w4.z; a0[3] += x0 * w4.w;
    a1[0] += x1 * w4.x; a1[1] += x1 * w4.y; a1[2] += x1 * w4.z; a1[3] += x1 * w4.w;
  }
#pragma unroll
  for (int s = 0; s < 4; s++) {
    atomicAdd(out + (size_t)(row0 + rs) * 1024 + c + s, a0[s]);
    atomicAdd(out + (size_t)(row0 + rs + 4) * 1024 + c + s, a1[s]);
  }
}

// ---------------------------------------------------------------------------
extern "C" void kernel_launch(void* const* d_in, const int* in_sizes, int n_in,
                              void* d_out, int out_size, void* d_ws, size_t ws_size,
                              hipStream_t stream) {
  (void)in_sizes; (void)n_in; (void)out_size; (void)ws_size;
  const float* Q   = (const float*)d_in[0];
  const float* K   = (const float*)d_in[1];
  const float* V   = (const float*)d_in[2];
  const float* rpe = (const float*)d_in[3];
  const float* lng = (const float*)d_in[4];
  const float* lnb = (const float*)d_in[5];
  const float* Wq  = (const float*)d_in[6];
  const float* bq  = (const float*)d_in[7];
  const float* Wk  = (const float*)d_in[8];
  const float* bk  = (const float*)d_in[9];
  const float* Wv  = (const float*)d_in[10];
  const float* bv  = (const float*)d_in[11];
  const float* Wrk = (const float*)d_in[12];
  const float* brk = (const float*)d_in[13];
  const float* Wrv = (const float*)d_in[14];
  const float* brv = (const float*)d_in[15];
  const float* Wo  = (const float*)d_in[16];
  const float* bo  = (const float*)d_in[17];
  float* out = (float*)d_out;

  float* ws    = (float*)d_ws;
  float* q_ws  = ws;                    // 262144
  float* k_ws  = q_ws + 262144;         // 131072
  float* v_ws  = k_ws + 131072;         // 131072
  float* ut_ws = v_ws + 131072;         // 4194304  (reused as w_ws after k_dotp)
  float* S0_ws = ut_ws + 4194304;       // 4096
  float* Gu_ws = S0_ws + 4096;          // 4096
  float* s_ws  = Gu_ws + 4096;          // 524288   (scores, then p2)
  float* mu_ws = s_ws + 524288;         // 32768
  float* rs_ws = mu_ws + 32768;         // 32768
  float* M_ws  = rs_ws + 32768;         // 4096
  float* Z_ws  = M_ws + 4096;           // 4096
  float* C1_ws = Z_ws + 4096;           // 4096
  float* sc_ws = C1_ws + 4096;          // 4096
  float* qv_ws = sc_ws + 4096;          // 262144   (~23 MB total)
  float* w_ws  = ut_ws;                 // reuse

  k_zero<<<256, 256, 0, stream>>>(bq, bk, bv, bo, q_ws, k_ws, v_ws, qv_ws, out, Gu_ws);
  k_qkv<<<dim3(8, 32, 4), 256, 0, stream>>>(Q, K, V, Wq, Wk, Wv, q_ws, k_ws, v_ws);
  k_base<<<16, 256, 0, stream>>>(q_ws, k_ws, brk, S0_ws);
  k_uproj<<<dim3(8, 8, 8), 256, 0, stream>>>(q_ws, Wrk, lng, lnb, ut_ws, Gu_ws, S0_ws);
  k_dotp<<<dim3(4, 256), 128, 0, stream>>>(rpe, lng, ut_ws, Gu_ws, S0_ws, s_ws, mu_ws, rs_ws);
  k_attn_p<<<256, 256, 0, stream>>>(mu_ws, rs_ws, s_ws, M_ws, Z_ws, C1_ws);
  k_comb<<<1, 256, 0, stream>>>(M_ws, Z_ws, sc_ws);
  k_wun<<<dim3(2, 256), 256, 0, stream>>>(rpe, lng, lnb, s_ws, Z_ws, C1_ws, w_ws);
  k_qv<<<dim3(4, 128), 256, 0, stream>>>(w_ws, Wrv, qv_ws);
  k_out<<<dim3(4, 32, 4), 256, 0, stream>>>(qv_ws, v_ws, brv, Z_ws, sc_ws, Wo, out);
}